// Round 5
// baseline (190.486 us; speedup 1.0000x reference)
//
#include <hip/hip_runtime.h>

// ---------------------------------------------------------------------------
// SSIM R7: register-only, shuffle-horizontal. No LDS, no barriers, no fences.
// R4-R6 post-mortem: VALUBusy ~31% in all LDS variants -- latency-bound on
// the per-row LDS round trip (write -> fence -> b128 read) with too few
// decorrelated waves (occ ~30%) to hide it; R6 conflicts 2.4M.
// R7:
//  * lane = column. Vertical 7-row sliding sums in registers (7-slot ring,
//    static indices). Horizontal 7-col window via 4 __shfl_down + 4 adds
//    per stat (ds_bpermute: crossbar, conflict-free, overlaps VALU).
//  * strip = 63 out rows: 378 = 6*63 EXACT -> no row overlap, no row masks;
//    y-amp 6*69/384 = 1.078. 6 strips x 7 col-tiles (58 outs + 6 halo,
//    last 30) x 128 imgs = 5376 waves; 4 independent waves per 256-thr WG
//    (no intra-block sync) -> 1344 blocks.
//  * double-buffered 7-row prefetch: rows for block c+1 issued at top of
//    block c -> ~1 block (>500 cy) of load lead time.
//  * shuffle wrap garbage (lanes>=58) is a coherent pixel multiset ->
//    Cauchy-Schwarz keeps d2>0 (no NaN); masked by lane<ncols select.
//  * SSIM formula / constants verbatim from R4/R6 (both absmax 0.0).
// Predicted: ssim_main ~28 us, VALUBusy ~60%, LDS size 0, conflicts ~0,
// FETCH ~160-190 MB (not limiting).
// ---------------------------------------------------------------------------

#define H 384
#define W 384
#define IMGSZ (H * W)
#define OWIDTH 378
#define NIMG 128
#define NRS 6                 // row strips: 6 x 63 out rows = 378 exact
#define NCT 7                 // col tiles: 58 outputs each (last 30)
#define WPI (NRS * NCT)       // 42 waves per image
#define NWAVE (NIMG * WPI)    // 5376
#define WVPB 4                // waves per 256-thread block
#define NBLKM (NWAVE / WVPB)  // 1344 blocks

__device__ __forceinline__ float wave_reduce(float v) {
#pragma unroll
    for (int off = 32; off > 0; off >>= 1) v += __shfl_down(v, off, 64);
    return v;
}

// 7-tap horizontal window sum across lanes: lane c gets v[c]+...+v[c+6].
// a = pairs, b = quads; result = (quad + pair@c+4) + single@c+6.
__device__ __forceinline__ float win7(float v) {
    const float a = v + __shfl_down(v, 1, 64);
    const float b = a + __shfl_down(a, 2, 64);
    return (b + __shfl_down(a, 4, 64)) + __shfl_down(v, 6, 64);
}

// One output row: slide vertical window (ring slot S <- prefetched row J),
// horizontal 7-tap on all 4 stats, SSIM formula, masked accumulate.
#define STEP(J, S) do {                                                   \
    const float xo = xv[S], yo = yv[S];                                   \
    const float xn = pfx[J], yn = pfy[J];                                 \
    sx += xn - xo; sy += yn - yo;                                         \
    sq = fmaf(xn, xn, fmaf(yn, yn, fmaf(-xo, xo, fmaf(-yo, yo, sq))));    \
    sxy = fmaf(xn, yn, fmaf(-xo, yo, sxy));                               \
    xv[S] = xn; yv[S] = yn;                                               \
    const float Sx = win7(sx), Sy = win7(sy);                             \
    const float Sq = win7(sq), Sxy = win7(sxy);                           \
    const float p  = Sx * Sy;                                             \
    const float qq = fmaf(Sx, Sx, Sy * Sy);                               \
    const float n1 = fmaf(2.f, p, C1B);                                   \
    const float n2 = fmaf(98.f, Sxy, fmaf(-2.f, p, C2B));                 \
    const float d1 = qq + C1B;                                            \
    const float d2 = fmaf(49.f, Sq, C2B - qq);                            \
    const float s  = (n1 * n2) * __builtin_amdgcn_rcpf(d1 * d2);          \
    acc = lok ? acc + s : acc;                                            \
} while (0)

#define BLOCK7 do {                                                       \
    STEP(0, 6); STEP(1, 0); STEP(2, 1); STEP(3, 2);                       \
    STEP(4, 3); STEP(5, 4); STEP(6, 5);                                   \
} while (0)

__global__ __launch_bounds__(256, 5) void ssim_main(const float* __restrict__ pred,
                                                    const float* __restrict__ act,
                                                    float* __restrict__ partials) {
    const int t = threadIdx.x;
    const int lane = t & 63;
    const int wid = blockIdx.x * WVPB + (t >> 6);
    const int img = wid / WPI;
    const int rem = wid - img * WPI;
    const int rs = rem / NCT;
    const int ct = rem - rs * NCT;

    const int y0 = rs * 63;                    // input rows y0..y0+68 <= 383
    const int c0 = ct * 58;
    const int nc_raw = OWIDTH - c0;
    const int ncols = (nc_raw < 58) ? nc_raw : 58;   // 58, or 30 for ct==6
    const bool lok = lane < ncols;

    int col = c0 + lane;                       // ct=6: lanes>=36 clamp (masked)
    col = (col < W) ? col : (W - 1);           // lane 35 -> col 383 exactly real
    const float* px = pred + (size_t)img * IMGSZ + (size_t)y0 * W + col;
    const float* py = act  + (size_t)img * IMGSZ + (size_t)y0 * W + col;

    const float C1B = 0.2401f;                 // C1 * 49^2
    const float C2B = 2.1168f;                 // C2 * 48*49
    float acc = 0.f;

    // ---- prologue: ring <- rows 0..5 (slot 6 = virtual row -1 = 0) ----
    float xv[7], yv[7];
#pragma unroll
    for (int i = 0; i < 6; ++i) { xv[i] = px[i * W]; yv[i] = py[i * W]; }
    xv[6] = 0.f; yv[6] = 0.f;
    float sx = 0.f, sy = 0.f, sq = 0.f, sxy = 0.f;
#pragma unroll
    for (int i = 0; i < 6; ++i) {
        sx += xv[i]; sy += yv[i];
        sq = fmaf(xv[i], xv[i], fmaf(yv[i], yv[i], sq));
        sxy = fmaf(xv[i], yv[i], sxy);
    }
    // pf buffer <- rows 6..12 (block 0's consume set)
    float pfx[7], pfy[7];
#pragma unroll
    for (int i = 0; i < 7; ++i) { pfx[i] = px[(6 + i) * W]; pfy[i] = py[(6 + i) * W]; }

    // ---- main: 8 blocks with double-buffered prefetch + peeled last ----
    const float* qx = px + 13 * W;             // next prefetch base (row 13)
    const float* qy = py + 13 * W;
    for (int c = 0; c < 8; ++c) {
        float nfx[7], nfy[7];
#pragma unroll
        for (int i = 0; i < 7; ++i) { nfx[i] = qx[i * W]; nfy[i] = qy[i * W]; }
        qx += 7 * W; qy += 7 * W;
        BLOCK7;                                // out rows 7c..7c+6 (rows 7c+6..7c+12)
#pragma unroll
        for (int i = 0; i < 7; ++i) { pfx[i] = nfx[i]; pfy[i] = nfy[i]; }
    }
    BLOCK7;                                    // out rows 56..62 (rows 62..68)

    // ---- per-wave partial (no cross-wave communication) ----
    const float wsum = wave_reduce(acc);
    if (lane == 0) partials[wid] = wsum;
}

__global__ __launch_bounds__(1024) void ssim_finalize(const float* __restrict__ partials,
                                                      float* __restrict__ out) {
    __shared__ double red[1024];
    const int t = threadIdx.x;
    double s = 0.0;
    for (int i = t; i < NWAVE; i += 1024) s += (double)partials[i];
    red[t] = s;
    __syncthreads();
#pragma unroll
    for (int off = 512; off > 0; off >>= 1) {
        if (t < off) red[t] += red[t + off];
        __syncthreads();
    }
    if (t == 0) out[0] = (float)(red[0] / ((double)NIMG * OWIDTH * OWIDTH));
}

extern "C" void kernel_launch(void* const* d_in, const int* in_sizes, int n_in,
                              void* d_out, int out_size, void* d_ws, size_t ws_size,
                              hipStream_t stream) {
    const float* pred = (const float*)d_in[0];
    const float* act  = (const float*)d_in[1];
    float* partials = (float*)d_ws;            // NWAVE floats, fully overwritten
    ssim_main<<<NBLKM, 256, 0, stream>>>(pred, act, partials);
    ssim_finalize<<<1, 1024, 0, stream>>>(partials, (float*)d_out);
}

// Round 6
// 190.141 us; speedup vs baseline: 1.0018x; 1.0018x over previous
//
#include <hip/hip_runtime.h>

// ---------------------------------------------------------------------------
// SSIM R8 = R7 (register-only, shuffle-horizontal, zero LDS/barriers in the
// hot path) with 3x the wave count.
// R7 post-mortem: correct + conflict-free, but 84.8 us with occ 35%,
// VALUBusy 29% -- GRID-STARVED: 5376 waves = 5.25 blocks/CU, ~2-3 waves/SIMD
// can't hide the dependent ds_bpermute chains (win7 depth ~2-3 shuffle
// latencies per row). DS-throughput floor is ~18-35 us; we sat 3-4x above.
// R8:
//  * strip = 21 out rows (378 = 18*21 exact, still no row overlap/masks).
//    18 strips x 7 col-tiles x 128 imgs = 16128 waves = 63 waves/CU in
//    4032 blocks; __launch_bounds__(256,8) -> 32 resident waves/CU.
//  * per-wave work: 27 input rows (6 ring init + 21 slides), 3 BLOCK7s,
//    double-buffered 7-row prefetch (unchanged pattern).
//  * partials: one per BLOCK (4032, fits prior workspace) via a single
//    end-of-kernel 4-float LDS reduce (16 B, one barrier, outside loops).
//  * win7 / STEP / SSIM formula / constants bit-identical to R7 (absmax 0).
// Predicted: occ ~80%, VALUBusy ~60%, ssim_main ~30-38 us, FETCH ~120 MB,
// conflicts ~0, VGPR <= 64 (8 waves/SIMD).
// ---------------------------------------------------------------------------

#define H 384
#define W 384
#define IMGSZ (H * W)
#define OWIDTH 378
#define NIMG 128
#define SY 21                 // out rows per strip
#define NRS 18                // 18 * 21 = 378 exact
#define NCT 7                 // col tiles: 58 outputs each (last 30)
#define WPI (NRS * NCT)       // 126 waves per image
#define NWAVE (NIMG * WPI)    // 16128
#define WVPB 4                // waves per 256-thread block
#define NBLKM (NWAVE / WVPB)  // 4032 blocks == partial count

__device__ __forceinline__ float wave_reduce(float v) {
#pragma unroll
    for (int off = 32; off > 0; off >>= 1) v += __shfl_down(v, off, 64);
    return v;
}

// 7-tap horizontal window sum across lanes: lane c gets v[c]+...+v[c+6].
__device__ __forceinline__ float win7(float v) {
    const float a = v + __shfl_down(v, 1, 64);
    const float b = a + __shfl_down(a, 2, 64);
    return (b + __shfl_down(a, 4, 64)) + __shfl_down(v, 6, 64);
}

// One output row: slide vertical window (ring slot S <- prefetched row J),
// horizontal 7-tap on all 4 stats, SSIM formula, masked accumulate.
#define STEP(J, S) do {                                                   \
    const float xo = xv[S], yo = yv[S];                                   \
    const float xn = pfx[J], yn = pfy[J];                                 \
    sx += xn - xo; sy += yn - yo;                                         \
    sq = fmaf(xn, xn, fmaf(yn, yn, fmaf(-xo, xo, fmaf(-yo, yo, sq))));    \
    sxy = fmaf(xn, yn, fmaf(-xo, yo, sxy));                               \
    xv[S] = xn; yv[S] = yn;                                               \
    const float Sx = win7(sx), Sy = win7(sy);                             \
    const float Sq = win7(sq), Sxy = win7(sxy);                           \
    const float p  = Sx * Sy;                                             \
    const float qq = fmaf(Sx, Sx, Sy * Sy);                               \
    const float n1 = fmaf(2.f, p, C1B);                                   \
    const float n2 = fmaf(98.f, Sxy, fmaf(-2.f, p, C2B));                 \
    const float d1 = qq + C1B;                                            \
    const float d2 = fmaf(49.f, Sq, C2B - qq);                            \
    const float s  = (n1 * n2) * __builtin_amdgcn_rcpf(d1 * d2);          \
    acc = lok ? acc + s : acc;                                            \
} while (0)

#define BLOCK7 do {                                                       \
    STEP(0, 6); STEP(1, 0); STEP(2, 1); STEP(3, 2);                       \
    STEP(4, 3); STEP(5, 4); STEP(6, 5);                                   \
} while (0)

__global__ __launch_bounds__(256, 8) void ssim_main(const float* __restrict__ pred,
                                                    const float* __restrict__ act,
                                                    float* __restrict__ partials) {
    __shared__ float red[WVPB];

    const int t = threadIdx.x;
    const int lane = t & 63;
    const int w = t >> 6;
    const int wid = blockIdx.x * WVPB + w;
    const int img = wid / WPI;
    const int rem = wid - img * WPI;
    const int rs = rem / NCT;
    const int ct = rem - rs * NCT;

    const int y0 = rs * SY;                    // input rows y0..y0+26 <= 383
    const int c0 = ct * 58;
    const int nc_raw = OWIDTH - c0;
    const int ncols = (nc_raw < 58) ? nc_raw : 58;   // 58, or 30 for ct==6
    const bool lok = lane < ncols;

    int col = c0 + lane;                       // ct=6: lanes>=36 clamp (masked)
    col = (col < W) ? col : (W - 1);
    const float* px = pred + (size_t)img * IMGSZ + (size_t)y0 * W + col;
    const float* py = act  + (size_t)img * IMGSZ + (size_t)y0 * W + col;

    const float C1B = 0.2401f;                 // C1 * 49^2
    const float C2B = 2.1168f;                 // C2 * 48*49
    float acc = 0.f;

    // ---- prologue: ring <- rows 0..5 (slot 6 = virtual row -1 = 0) ----
    float xv[7], yv[7];
#pragma unroll
    for (int i = 0; i < 6; ++i) { xv[i] = px[i * W]; yv[i] = py[i * W]; }
    xv[6] = 0.f; yv[6] = 0.f;
    float sx = 0.f, sy = 0.f, sq = 0.f, sxy = 0.f;
#pragma unroll
    for (int i = 0; i < 6; ++i) {
        sx += xv[i]; sy += yv[i];
        sq = fmaf(xv[i], xv[i], fmaf(yv[i], yv[i], sq));
        sxy = fmaf(xv[i], yv[i], sxy);
    }
    // pf buffer <- rows 6..12 (first BLOCK7's consume set)
    float pfx[7], pfy[7];
#pragma unroll
    for (int i = 0; i < 7; ++i) { pfx[i] = px[(6 + i) * W]; pfy[i] = py[(6 + i) * W]; }

    // ---- main: 2 double-buffered blocks + peeled last ----
    const float* qx = px + 13 * W;             // next prefetch base (row 13)
    const float* qy = py + 13 * W;
#pragma unroll 1
    for (int c = 0; c < 2; ++c) {
        float nfx[7], nfy[7];
#pragma unroll
        for (int i = 0; i < 7; ++i) { nfx[i] = qx[i * W]; nfy[i] = qy[i * W]; }
        qx += 7 * W; qy += 7 * W;
        BLOCK7;                                // out rows 7c..7c+6
#pragma unroll
        for (int i = 0; i < 7; ++i) { pfx[i] = nfx[i]; pfy[i] = nfy[i]; }
    }
    BLOCK7;                                    // out rows 14..20 (input rows 20..26)

    // ---- block partial: one barrier, outside all loops ----
    const float wsum = wave_reduce(acc);
    if (lane == 0) red[w] = wsum;
    __syncthreads();
    if (t == 0) partials[blockIdx.x] = (red[0] + red[1]) + (red[2] + red[3]);
}

__global__ __launch_bounds__(1024) void ssim_finalize(const float* __restrict__ partials,
                                                      float* __restrict__ out) {
    __shared__ double red[1024];
    const int t = threadIdx.x;
    double s = 0.0;
    for (int i = t; i < NBLKM; i += 1024) s += (double)partials[i];
    red[t] = s;
    __syncthreads();
#pragma unroll
    for (int off = 512; off > 0; off >>= 1) {
        if (t < off) red[t] += red[t + off];
        __syncthreads();
    }
    if (t == 0) out[0] = (float)(red[0] / ((double)NIMG * OWIDTH * OWIDTH));
}

extern "C" void kernel_launch(void* const* d_in, const int* in_sizes, int n_in,
                              void* d_out, int out_size, void* d_ws, size_t ws_size,
                              hipStream_t stream) {
    const float* pred = (const float*)d_in[0];
    const float* act  = (const float*)d_in[1];
    float* partials = (float*)d_ws;            // NBLKM (4032) floats
    ssim_main<<<NBLKM, 256, 0, stream>>>(pred, act, partials);
    ssim_finalize<<<1, 1024, 0, stream>>>(partials, (float*)d_out);
}

// Round 7
// 166.681 us; speedup vs baseline: 1.1428x; 1.1407x over previous
//
#include <hip/hip_runtime.h>

// ---------------------------------------------------------------------------
// SSIM R9: DPP-horizontal, packed-f32, zero-DS hot loop.
// R7/R8 post-mortem: identical 84.7/84.8 us at 2x occupancy and identical
// bpermute totals (5.42M) -> ds_bpermute-throughput-bound (~9.6 cyc each,
// DS pipe saturated). Fix = remove the shuffles, not add waves.
// R9:
//  * 16-lane group owns 32 consecutive cols (2/lane as float2), produces 26
//    outputs (lanes 0..12; 7-col windows stay inside the 16-lane DPP row).
//    Horizontal 7-tap via v_add_f32_dpp row_shl:1/2/3 -- VALU pipe, zero DS:
//    p=sa+sb; u=p+shl1(p); c=u+shl2(p); S0=c+shl3(sa); S1=sb+shl1(c).
//    4 DPP-adds per stat per 2 cols (was 16 bpermutes per 1 col).
//  * vertical slide + SSIM formula in packed f32 (ext_vector float2 ->
//    v_pk_fma_f32), ~halving their VALU count.
//  * masked lanes (l>12 / col>=378 / tile 15): windows are consistent
//    sub-sums -> Cauchy-Schwarz keeps d2>=C2B>0, no NaN -> mask is one
//    packed fma with a precomputed 0/1 pair.
//  * tiles stride 26 cols; 4 waves x 4 groups = 16 tiles cover a row-band
//    (tile 15 fully masked). 18 bands x 21 rows x 128 imgs = 9216 waves in
//    2304 blocks. float2 loads clamped to col 382 (no OOB).
//  * ring/prefetch skeleton identical to R8 (passed, absmax 0.0).
// Predicted: ssim_main ~33-40 us, VALUBusy 55-75%, DS ~0, FETCH ~150 MB.
// ---------------------------------------------------------------------------

typedef float v2f __attribute__((ext_vector_type(2)));

#define H 384
#define W 384
#define IMGSZ (H * W)
#define OWIDTH 378
#define NIMG 128
#define SY 21
#define NBANDS 18             // 18*21 = 378 exact
#define NCW 4                 // col-waves per band (4 waves x 4 groups = 16 tiles)
#define WPI (NBANDS * NCW)    // 72 waves per image
#define NWAVE (NIMG * WPI)    // 9216
#define WVPB 4                // waves per 256-thread block
#define NBLKM (NWAVE / WVPB)  // 2304 blocks == partial count

#define SHL1 0x101            // DPP row_shl:1  (lane i <- lane i+1, in-row)
#define SHL2 0x102
#define SHL3 0x103

template <int CTRL>
__device__ __forceinline__ float dshl(float v) {
    return __int_as_float(__builtin_amdgcn_update_dpp(
        0, __float_as_int(v), CTRL, 0xF, 0xF, true));  // bound_ctrl: 0-fill
}

#define FMA2(A, B, C) __builtin_elementwise_fma((A), (B), (C))

__device__ __forceinline__ float wave_reduce(float v) {
#pragma unroll
    for (int off = 32; off > 0; off >>= 1) v += __shfl_down(v, off, 64);
    return v;
}

// Horizontal 7-tap for a packed stat pair S2={s(2l),s(2l+1)} -> O2 windows.
#define HOR(S2, O2) do {                                                  \
    const float p_ = (S2).x + (S2).y;                                     \
    const float u_ = p_ + dshl<SHL1>(p_);                                 \
    const float c_ = u_ + dshl<SHL2>(p_);                                 \
    (O2).x = c_ + dshl<SHL3>((S2).x);                                     \
    (O2).y = (S2).y + dshl<SHL1>(c_);                                     \
} while (0)

// One output row: vertical slide (ring slot S <- prefetched row J), DPP
// horizontal on 4 stats, packed SSIM formula, masked packed accumulate.
#define STEP(J, S) do {                                                   \
    const v2f xn = pfx[J], yn = pfy[J];                                   \
    const v2f xo = rx[S],  yo = ry[S];                                    \
    sx2 += xn - xo;                                                       \
    sy2 += yn - yo;                                                       \
    sq2 = FMA2(xn, xn, FMA2(yn, yn, FMA2(-xo, xo, FMA2(-yo, yo, sq2)))); \
    sw2 = FMA2(xn, yn, FMA2(-xo, yo, sw2));                               \
    rx[S] = xn; ry[S] = yn;                                               \
    v2f Sx2, Sy2, Sq2, Sw2;                                               \
    HOR(sx2, Sx2); HOR(sy2, Sy2); HOR(sq2, Sq2); HOR(sw2, Sw2);           \
    const v2f p2  = Sx2 * Sy2;                                            \
    const v2f qq2 = FMA2(Sx2, Sx2, Sy2 * Sy2);                            \
    const v2f n12 = FMA2((v2f)2.f, p2, (v2f)C1B);                         \
    const v2f n22 = FMA2((v2f)98.f, Sw2, FMA2((v2f)(-2.f), p2, (v2f)C2B));\
    const v2f d12 = qq2 + (v2f)C1B;                                       \
    const v2f d22 = FMA2((v2f)49.f, Sq2, (v2f)C2B - qq2);                 \
    const v2f den = d12 * d22;                                            \
    v2f r2;                                                               \
    r2.x = __builtin_amdgcn_rcpf(den.x);                                  \
    r2.y = __builtin_amdgcn_rcpf(den.y);                                  \
    acc2 = FMA2(n12 * n22 * r2, msk2, acc2);                              \
} while (0)

#define BLOCK7 do {                                                       \
    STEP(0, 6); STEP(1, 0); STEP(2, 1); STEP(3, 2);                       \
    STEP(4, 3); STEP(5, 4); STEP(6, 5);                                   \
} while (0)

__global__ __launch_bounds__(256, 4) void ssim_main(const float* __restrict__ pred,
                                                    const float* __restrict__ act,
                                                    float* __restrict__ partials) {
    __shared__ float red[WVPB];

    const int t = threadIdx.x;
    const int lane = t & 63;
    const int w = t >> 6;
    const int wid = blockIdx.x * WVPB + w;
    const int img = wid / WPI;
    const int rem = wid - img * WPI;
    const int band = rem >> 2;                 // 0..17
    const int cw = rem & 3;                    // 0..3
    const int l = lane & 15;                   // lane in 16-lane DPP row
    const int g = lane >> 4;                   // group 0..3
    const int tile = cw * 4 + g;               // 0..15 (tile 15 fully masked)
    const int ca = tile * 26 + 2 * l;          // first owned column
    const bool oka = (l <= 12) && (ca < OWIDTH);
    const bool okb = (l <= 12) && (ca + 1 < OWIDTH);
    v2f msk2; msk2.x = oka ? 1.f : 0.f; msk2.y = okb ? 1.f : 0.f;
    const int coff = (ca < 382) ? ca : 382;    // float2 load stays in-bounds
    const int y0 = band * SY;                  // input rows y0..y0+26 <= 383

    const float* bx = pred + (size_t)img * IMGSZ + (size_t)y0 * W + coff;
    const float* by = act  + (size_t)img * IMGSZ + (size_t)y0 * W + coff;

    const float C1B = 0.2401f;                 // C1 * 49^2
    const float C2B = 2.1168f;                 // C2 * 48*49

    // ---- prologue: ring <- rows 0..5 (slot 6 = virtual row -1 = 0) ----
    v2f rx[7], ry[7];
#pragma unroll
    for (int i = 0; i < 6; ++i) {
        rx[i] = *(const v2f*)(bx + i * W);
        ry[i] = *(const v2f*)(by + i * W);
    }
    rx[6] = (v2f)0.f; ry[6] = (v2f)0.f;
    v2f sx2 = (v2f)0.f, sy2 = (v2f)0.f, sq2 = (v2f)0.f, sw2 = (v2f)0.f;
#pragma unroll
    for (int i = 0; i < 6; ++i) {
        sx2 += rx[i]; sy2 += ry[i];
        sq2 = FMA2(rx[i], rx[i], FMA2(ry[i], ry[i], sq2));
        sw2 = FMA2(rx[i], ry[i], sw2);
    }
    // pf <- rows 6..12 (first BLOCK7's consume set)
    v2f pfx[7], pfy[7];
#pragma unroll
    for (int i = 0; i < 7; ++i) {
        pfx[i] = *(const v2f*)(bx + (6 + i) * W);
        pfy[i] = *(const v2f*)(by + (6 + i) * W);
    }
    v2f acc2 = (v2f)0.f;

    // ---- main: 2 double-buffered BLOCK7s + peeled last (21 out rows) ----
    const float* qx = bx + 13 * W;
    const float* qy = by + 13 * W;
#pragma unroll 1
    for (int c = 0; c < 2; ++c) {
        v2f nfx[7], nfy[7];
#pragma unroll
        for (int i = 0; i < 7; ++i) {
            nfx[i] = *(const v2f*)(qx + i * W);
            nfy[i] = *(const v2f*)(qy + i * W);
        }
        qx += 7 * W; qy += 7 * W;
        BLOCK7;
#pragma unroll
        for (int i = 0; i < 7; ++i) { pfx[i] = nfx[i]; pfy[i] = nfy[i]; }
    }
    BLOCK7;

    // ---- block partial: one barrier, outside all loops ----
    const float wsum = wave_reduce(acc2.x + acc2.y);
    if (lane == 0) red[w] = wsum;
    __syncthreads();
    if (t == 0) partials[blockIdx.x] = (red[0] + red[1]) + (red[2] + red[3]);
}

__global__ __launch_bounds__(1024) void ssim_finalize(const float* __restrict__ partials,
                                                      float* __restrict__ out) {
    __shared__ double red[1024];
    const int t = threadIdx.x;
    double s = 0.0;
    for (int i = t; i < NBLKM; i += 1024) s += (double)partials[i];
    red[t] = s;
    __syncthreads();
#pragma unroll
    for (int off = 512; off > 0; off >>= 1) {
        if (t < off) red[t] += red[t + off];
        __syncthreads();
    }
    if (t == 0) out[0] = (float)(red[0] / ((double)NIMG * OWIDTH * OWIDTH));
}

extern "C" void kernel_launch(void* const* d_in, const int* in_sizes, int n_in,
                              void* d_out, int out_size, void* d_ws, size_t ws_size,
                              hipStream_t stream) {
    const float* pred = (const float*)d_in[0];
    const float* act  = (const float*)d_in[1];
    float* partials = (float*)d_ws;            // NBLKM (2304) floats
    ssim_main<<<NBLKM, 256, 0, stream>>>(pred, act, partials);
    ssim_finalize<<<1, 1024, 0, stream>>>(partials, (float*)d_out);
}